// Round 2
// baseline (514.686 us; speedup 1.0000x reference)
//
#include <hip/hip_runtime.h>
#include <cstdint>
#include <cstddef>

#define F_ALPHA 0.5f
#define THRESH  0.5f
#define EPS8    1e-8f
#define EPS7    1e-7f
#define MAXM    64
#define CCLS    21
#define MCH     10     // ioubuf chunk rows (keeps LDS ~13KB -> full occupancy)
#define NSCAN   25     // scanners per row in bp reduce

// ---------------------------------------------------------------------------
// Kernel A: per-prior best GT (bt) + per-GT best prior (bp) matching.
// grid = (ceil(P/256), B), block = 256.
// ioubuf is chunked: MCH rows of 257 floats (stride 257 = conflict-free for
// the stride-1 write phase, ~4-way for the stride-25 scan phase).
// ---------------------------------------------------------------------------
__global__ __launch_bounds__(256, 6)
void match_kernel(const float4* __restrict__ dbox,
                  const float4* __restrict__ gt,
                  unsigned long long* __restrict__ bpkey,
                  unsigned char* __restrict__ match,
                  int P, int M)
{
    __shared__ float4 tb[MAXM];
    __shared__ float  tarea[MAXM];
    __shared__ float  ioubuf[MCH * 257];
    __shared__ float  pval[MCH * NSCAN];
    __shared__ int    pidx[MCH * NSCAN];

    const int t = threadIdx.x;
    const int b = blockIdx.y;
    const int p = blockIdx.x * 256 + t;
    const bool valid = (p < P);

    if (t < M) {
        float4 g = gt[(size_t)b * M + t];
        tb[t] = g;
        tarea[t] = (g.z - g.x) * (g.w - g.y);
    }
    __syncthreads();

    float4 d = valid ? dbox[p] : make_float4(0.f, 0.f, 0.f, 0.f);
    float darea = (d.z - d.x) * (d.w - d.y);

    float best = -1.0f;     // bt running max (strict > => first-index tie)
    int   bm = 0;

    for (int chunk = 0; chunk < M; chunk += MCH) {
        int rows = min(MCH, M - chunk);
        // compute ious for this chunk of GTs
        for (int r = 0; r < rows; r++) {
            int m = chunk + r;
            float iou;
            if (valid) {
                float4 g = tb[m];
                float lx = fmaxf(d.x, g.x), ly = fmaxf(d.y, g.y);
                float rx = fminf(d.z, g.z), ry = fminf(d.w, g.w);
                float w = fmaxf(rx - lx, 0.f), h = fmaxf(ry - ly, 0.f);
                float inter = w * h;
                iou = inter / (darea + tarea[m] - inter);
            } else {
                iou = -1.0f;    // never wins any comparison vs valid (>=0) ious
            }
            ioubuf[r * 257 + t] = iou;
            if (iou > best) { best = iou; bm = m; }
        }
        __syncthreads();
        // bp partial scan: NSCAN strided scanners per row
        if (t < rows * NSCAN) {
            int row = t / NSCAN, s = t % NSCAN;
            float bv = -2.0f; int bj = 0;
            for (int j = s; j < 256; j += NSCAN) {      // j ascending: > keeps first
                float v = ioubuf[row * 257 + j];
                if (v > bv) { bv = v; bj = j; }
            }
            pval[t] = bv; pidx[t] = bj;
        }
        __syncthreads();
        // combine + device atomicMax
        if (t < rows) {
            float bv = -2.0f; int bj = 1 << 30;
            for (int s = 0; s < NSCAN; s++) {
                float v = pval[t * NSCAN + s]; int j = pidx[t * NSCAN + s];
                if (v > bv || (v == bv && j < bj)) { bv = v; bj = j; }
            }
            unsigned pp = blockIdx.x * 256 + (unsigned)bj;
            // key: larger iou wins; tie -> smaller p (jnp.argmax picks first)
            unsigned long long key = ((unsigned long long)__float_as_uint(bv) << 32)
                                   | (unsigned long long)(0xFFFFFFFFu - pp);
            atomicMax(&bpkey[(size_t)b * M + (chunk + t)], key);
        }
        // next chunk's ioubuf writes are fenced by its own first barrier:
        // all threads pass the pval barrier before any rewrite of ioubuf,
        // and combine threads rejoin at the next chunk's first barrier.
        __syncthreads();
    }

    if (valid) {
        unsigned char code = (unsigned char)((best >= THRESH ? 0x40 : 0) | bm);
        match[(size_t)b * P + p] = code;
    }
}

// ---------------------------------------------------------------------------
// Kernel B: focal loss on every anchor (conf staged via LDS, coalesced) +
// GIoU on positives + fused force-match resolution + fused final division
// (last block via ticket).
// ---------------------------------------------------------------------------
__global__ __launch_bounds__(256, 4)
void loss_kernel(const float4* __restrict__ locp,
                 const float*  __restrict__ conf,
                 const float4* __restrict__ dbox,
                 const float4* __restrict__ gt,
                 const int*    __restrict__ gtl,
                 const unsigned long long* __restrict__ bpkey,
                 const unsigned char* __restrict__ match,
                 double* __restrict__ S,
                 unsigned int* __restrict__ NP,
                 unsigned int* __restrict__ ticket,
                 float* __restrict__ out,
                 int P, int M)
{
    __shared__ float    scf[256 * CCLS];   // 21504 B conf tile
    __shared__ float4   tb[MAXM];
    __shared__ int      tl[MAXM];
    __shared__ unsigned bpp[MAXM];
    __shared__ double   sv[4];
    __shared__ int      sc[4];

    const int t = threadIdx.x;
    const int b = blockIdx.y;
    const int p0 = blockIdx.x * 256;
    const int p = p0 + t;

    if (t < M) {
        tb[t] = gt[(size_t)b * M + t];
        tl[t] = gtl[(size_t)b * M + t];
        bpp[t] = 0xFFFFFFFFu - (unsigned)(bpkey[(size_t)b * M + t] & 0xFFFFFFFFull);
    }

    // ---- stage conf tile: contiguous [cnt*21] floats, coalesced float4 ----
    const int cnt = min(256, P - p0);
    const int nf = cnt * CCLS;
    const float* src = conf + ((size_t)b * P + p0) * CCLS;
    if (((uintptr_t)src & 15) == 0) {
        const int n4 = nf >> 2;
        const float4* s4 = (const float4*)src;
        float4* d4 = (float4*)scf;
        for (int i = t; i < n4; i += 256) d4[i] = s4[i];
        for (int i = (n4 << 2) + t; i < nf; i += 256) scf[i] = src[i];
    } else {
        for (int i = t; i < nf; i += 256) scf[i] = src[i];
    }
    __syncthreads();

    double acc = 0.0;
    int cnt_pos = 0;
    if (p < P) {
        unsigned char code = match[(size_t)b * P + p];
        int  idx = code & 0x3F;
        bool pos = (code & 0x40) != 0;
        // force-match: last GT whose best prior is p wins (scatter last-wins)
        for (int j = 0; j < M; j++) {
            if (bpp[j] == (unsigned)p) { idx = j; pos = true; }
        }
        int lbl = pos ? tl[idx] : 0;

        // ---- focal loss (from LDS; stride 21 -> <=2 lanes/bank, free) ----
        const float* x = scf + t * CCLS;
        float mx = -1e30f;
        #pragma unroll
        for (int c = 0; c < CCLS; c++) mx = fmaxf(mx, x[c]);
        float sum = 0.f;
        #pragma unroll
        for (int c = 0; c < CCLS; c++) sum += expf(x[c] - mx);
        float ce = (mx + logf(sum)) - x[lbl];
        float pt = expf(-ce);
        float om = 1.f - pt;
        acc = (double)(F_ALPHA * om * sqrtf(om) * ce);  // (1-pt)^1.5

        // ---- GIoU for positives ----
        if (pos) {
            cnt_pos = 1;
            float4 d = dbox[p];
            float dw = d.z - d.x, dh = d.w - d.y;
            float dcx = d.x + dw * 0.5f, dcy = d.y + dh * 0.5f;
            float4 g = tb[idx];
            float gw = g.z - g.x, gh = g.w - g.y;
            float gcx = g.x + gw * 0.5f, gcy = g.y + gh * 0.5f;
            // encode target vs anchor, then decode (matches reference ops)
            float ex = (gcx - dcx) / (dw + EPS8);
            float ey = (gcy - dcy) / (dh + EPS8);
            float ew = logf(gw / (dw + EPS8) + EPS8);
            float eh = logf(gh / (dh + EPS8) + EPS8);
            float tcx = ex * dw + dcx, tcy = ey * dh + dcy;
            float tw = expf(ew) * dw,  th = expf(eh) * dh;
            float t0 = tcx - tw * 0.5f, t1 = tcy - th * 0.5f;
            float t2 = tcx + tw * 0.5f, t3 = tcy + th * 0.5f;
            // decode prediction
            float4 l = locp[(size_t)b * P + p];
            float pcx = l.x * dw + dcx, pcy = l.y * dh + dcy;
            float pw = expf(l.z) * dw,  ph = expf(l.w) * dh;
            float q0 = pcx - pw * 0.5f, q1 = pcy - ph * 0.5f;
            float q2 = pcx + pw * 0.5f, q3 = pcy + ph * 0.5f;
            // giou
            float ix0 = fmaxf(q0, t0), iy0 = fmaxf(q1, t1);
            float ix1 = fminf(q2, t2), iy1 = fminf(q3, t3);
            float iw = fmaxf(ix1 - ix0, 0.f), ih = fmaxf(iy1 - iy0, 0.f);
            float inter = iw * ih;
            float pa = (q2 - q0) * (q3 - q1);
            float ta = (t2 - t0) * (t3 - t1);
            float uni = pa + ta - inter;
            float iou = inter / (uni + EPS7);
            float e0 = fminf(q0, t0), e1 = fminf(q1, t1);
            float e2 = fmaxf(q2, t2), e3 = fmaxf(q3, t3);
            float ewd = fmaxf(e2 - e0, 0.f), ehd = fmaxf(e3 - e1, 0.f);
            float encl = ewd * ehd;
            float giou = iou - (encl - uni) / (encl + EPS7);
            acc += (double)(1.f - giou);
        }
    }

    // ---- block reduce ----
    for (int o = 32; o > 0; o >>= 1) {
        acc += __shfl_down(acc, o, 64);
        cnt_pos += __shfl_down(cnt_pos, o, 64);
    }
    int w = t >> 6, lane = t & 63;
    if (lane == 0) { sv[w] = acc; sc[w] = cnt_pos; }
    __syncthreads();
    if (t == 0) {
        double a = sv[0] + sv[1] + sv[2] + sv[3];
        int    c = sc[0] + sc[1] + sc[2] + sc[3];
        atomicAdd(S, a);
        atomicAdd(NP, (unsigned)c);
        __threadfence();
        unsigned total = gridDim.x * gridDim.y;
        unsigned fin = atomicAdd(ticket, 1u);
        if (fin == total - 1) {
            __threadfence();
            double s  = atomicAdd(S, 0.0);        // device-scope read
            unsigned n = atomicAdd(NP, 0u);
            out[0] = (n == 0) ? 0.0f : (float)(s / (double)n);
        }
    }
}

// ---------------------------------------------------------------------------
extern "C" void kernel_launch(void* const* d_in, const int* in_sizes, int n_in,
                              void* d_out, int out_size, void* d_ws, size_t ws_size,
                              hipStream_t stream)
{
    const float* locp = (const float*)d_in[0];   // [B,P,4]
    const float* conf = (const float*)d_in[1];   // [B,P,C]
    const float* dbox = (const float*)d_in[2];   // [P,4]
    const float* gt   = (const float*)d_in[3];   // [B,M,4]
    const int*   gtl  = (const int*)d_in[4];     // [B,M]

    const int P  = in_sizes[2] / 4;
    const long long BP = (long long)in_sizes[0] / 4;
    const int B  = (int)(BP / P);
    const int M  = in_sizes[4] / B;

    // ws layout: bpkey[B*M] u64 | S f64 | NP u32 | ticket u32 | match[B*P] u8
    char* ws = (char*)d_ws;
    unsigned long long* bpkey = (unsigned long long*)ws;
    size_t off = ((size_t)B * M * 8 + 7) & ~(size_t)7;
    double*       Sacc   = (double*)(ws + off);
    unsigned int* NP     = (unsigned int*)(ws + off + 8);
    unsigned int* ticket = (unsigned int*)(ws + off + 12);
    unsigned char* match = (unsigned char*)(ws + off + 16);

    hipMemsetAsync(d_ws, 0, off + 16, stream);   // bpkey + S + NP + ticket

    const int nblk = (P + 255) / 256;
    dim3 grid(nblk, B);
    match_kernel<<<grid, 256, 0, stream>>>((const float4*)dbox, (const float4*)gt,
                                           bpkey, match, P, M);
    loss_kernel<<<grid, 256, 0, stream>>>((const float4*)locp, conf,
                                          (const float4*)dbox, (const float4*)gt,
                                          gtl, bpkey, match, Sacc, NP, ticket,
                                          (float*)d_out, P, M);
}

// Round 3
// 309.286 us; speedup vs baseline: 1.6641x; 1.6641x over previous
//
#include <hip/hip_runtime.h>
#include <cstdint>
#include <cstddef>

#define F_ALPHA 0.5f
#define THRESH  0.5f
#define EPS8    1e-8f
#define EPS7    1e-7f
#define MAXM    64
#define CCLS    21
#define MCH     10     // ioubuf chunk rows
#define NSCAN   25     // scanners per row in bp reduce

// ---------------------------------------------------------------------------
// Kernel 0: init bpkey to key(iou=0, p=0)  -> argmax semantics for all-zero row
// ---------------------------------------------------------------------------
__global__ void init_kernel(unsigned long long* __restrict__ bpkey, int n)
{
    int i = blockIdx.x * 256 + threadIdx.x;
    if (i < n) bpkey[i] = 0x00000000FFFFFFFFull;   // iou bits 0, p = 0
}

// ---------------------------------------------------------------------------
// Kernel A: per-prior best GT (bt) + per-GT best prior (bp) matching.
// grid = (ceil(P/256), B), block = 256.
// ---------------------------------------------------------------------------
__global__ __launch_bounds__(256)
void match_kernel(const float4* __restrict__ dbox,
                  const float4* __restrict__ gt,
                  unsigned long long* __restrict__ bpkey,
                  unsigned char* __restrict__ match,
                  int P, int M)
{
    __shared__ float4 tb[MAXM];
    __shared__ float  tarea[MAXM];
    __shared__ float  ioubuf[MCH * 257];
    __shared__ float  pval[MCH * NSCAN];
    __shared__ int    pidx[MCH * NSCAN];

    const int t = threadIdx.x;
    const int b = blockIdx.y;
    const int p = blockIdx.x * 256 + t;
    const bool valid = (p < P);

    if (t < M) {
        float4 g = gt[(size_t)b * M + t];
        tb[t] = g;
        tarea[t] = (g.z - g.x) * (g.w - g.y);
    }
    __syncthreads();

    float4 d = valid ? dbox[p] : make_float4(0.f, 0.f, 0.f, 0.f);
    float darea = (d.z - d.x) * (d.w - d.y);

    float best = -1.0f;     // bt running max (strict > => first-index tie)
    int   bm = 0;

    for (int chunk = 0; chunk < M; chunk += MCH) {
        int rows = min(MCH, M - chunk);
        for (int r = 0; r < rows; r++) {
            int m = chunk + r;
            float iou;
            if (valid) {
                float4 g = tb[m];
                float lx = fmaxf(d.x, g.x), ly = fmaxf(d.y, g.y);
                float rx = fminf(d.z, g.z), ry = fminf(d.w, g.w);
                float w = fmaxf(rx - lx, 0.f), h = fmaxf(ry - ly, 0.f);
                float inter = w * h;
                // fast rcp: IoU only feeds compares, 1-ulp error harmless
                iou = inter * __builtin_amdgcn_rcpf(darea + tarea[m] - inter);
            } else {
                iou = -1.0f;
            }
            ioubuf[r * 257 + t] = iou;
            if (iou > best) { best = iou; bm = m; }
        }
        __syncthreads();
        if (t < rows * NSCAN) {
            int row = t / NSCAN, s = t % NSCAN;
            float bv = -2.0f; int bj = 0;
            for (int j = s; j < 256; j += NSCAN) {
                float v = ioubuf[row * 257 + j];
                if (v > bv) { bv = v; bj = j; }
            }
            pval[t] = bv; pidx[t] = bj;
        }
        __syncthreads();
        if (t < rows) {
            float bv = -2.0f; int bj = 1 << 30;
            for (int s = 0; s < NSCAN; s++) {
                float v = pval[t * NSCAN + s]; int j = pidx[t * NSCAN + s];
                if (v > bv || (v == bv && j < bj)) { bv = v; bj = j; }
            }
            // skip atomic when this block saw zero overlap for this GT
            // (init key already encodes iou=0,p=0 == global argmax fallback)
            if (bv > 0.0f) {
                unsigned pp = blockIdx.x * 256 + (unsigned)bj;
                unsigned long long key =
                    ((unsigned long long)__float_as_uint(bv) << 32)
                    | (unsigned long long)(0xFFFFFFFFu - pp);
                atomicMax(&bpkey[(size_t)b * M + (chunk + t)], key);
            }
        }
        __syncthreads();
    }

    if (valid) {
        unsigned char code = (unsigned char)((best >= THRESH ? 0x40 : 0) | bm);
        match[(size_t)b * P + p] = code;
    }
}

// ---------------------------------------------------------------------------
// Kernel B: focal loss on every anchor (conf via coalesced LDS staging) +
// GIoU on positives + fused force-match resolution.
// Per-block partials -> private ws slots (NO contended atomics, no fences).
// ---------------------------------------------------------------------------
__global__ __launch_bounds__(256)
void loss_kernel(const float4* __restrict__ locp,
                 const float*  __restrict__ conf,
                 const float4* __restrict__ dbox,
                 const float4* __restrict__ gt,
                 const int*    __restrict__ gtl,
                 const unsigned long long* __restrict__ bpkey,
                 const unsigned char* __restrict__ match,
                 double* __restrict__ partS,
                 int*    __restrict__ partC,
                 int P, int M)
{
    __shared__ float    scf[256 * CCLS];   // 21504 B conf tile
    __shared__ float4   tb[MAXM];
    __shared__ int      tl[MAXM];
    __shared__ unsigned bpp[MAXM];
    __shared__ double   sv[4];
    __shared__ int      sc[4];

    const int t = threadIdx.x;
    const int b = blockIdx.y;
    const int p0 = blockIdx.x * 256;
    const int p = p0 + t;

    if (t < M) {
        tb[t] = gt[(size_t)b * M + t];
        tl[t] = gtl[(size_t)b * M + t];
        bpp[t] = 0xFFFFFFFFu - (unsigned)(bpkey[(size_t)b * M + t] & 0xFFFFFFFFull);
    }

    // stage conf tile: contiguous [cnt*21] floats, coalesced float4
    const int cnt = min(256, P - p0);
    const int nf = cnt * CCLS;
    const float* src = conf + ((size_t)b * P + p0) * CCLS;
    if (((uintptr_t)src & 15) == 0) {
        const int n4 = nf >> 2;
        const float4* s4 = (const float4*)src;
        float4* d4 = (float4*)scf;
        for (int i = t; i < n4; i += 256) d4[i] = s4[i];
        for (int i = (n4 << 2) + t; i < nf; i += 256) scf[i] = src[i];
    } else {
        for (int i = t; i < nf; i += 256) scf[i] = src[i];
    }
    __syncthreads();

    double acc = 0.0;
    int cnt_pos = 0;
    if (p < P) {
        unsigned char code = match[(size_t)b * P + p];
        int  idx = code & 0x3F;
        bool pos = (code & 0x40) != 0;
        for (int j = 0; j < M; j++) {            // force-match, last-wins
            if (bpp[j] == (unsigned)p) { idx = j; pos = true; }
        }
        int lbl = pos ? tl[idx] : 0;

        // focal loss (precise expf/logf: 1.5M-term sum, bias matters)
        const float* x = scf + t * CCLS;
        float mx = -1e30f;
        #pragma unroll
        for (int c = 0; c < CCLS; c++) mx = fmaxf(mx, x[c]);
        float sum = 0.f;
        #pragma unroll
        for (int c = 0; c < CCLS; c++) sum += expf(x[c] - mx);
        float ce = (mx + logf(sum)) - x[lbl];
        float pt = expf(-ce);
        float om = 1.f - pt;
        acc = (double)(F_ALPHA * om * sqrtf(om) * ce);

        if (pos) {
            cnt_pos = 1;
            float4 d = dbox[p];
            float dw = d.z - d.x, dh = d.w - d.y;
            float dcx = d.x + dw * 0.5f, dcy = d.y + dh * 0.5f;
            float4 g = tb[idx];
            float gw = g.z - g.x, gh = g.w - g.y;
            float gcx = g.x + gw * 0.5f, gcy = g.y + gh * 0.5f;
            float ex = (gcx - dcx) / (dw + EPS8);
            float ey = (gcy - dcy) / (dh + EPS8);
            float ew = logf(gw / (dw + EPS8) + EPS8);
            float eh = logf(gh / (dh + EPS8) + EPS8);
            float tcx = ex * dw + dcx, tcy = ey * dh + dcy;
            float tw = expf(ew) * dw,  th = expf(eh) * dh;
            float t0 = tcx - tw * 0.5f, t1 = tcy - th * 0.5f;
            float t2 = tcx + tw * 0.5f, t3 = tcy + th * 0.5f;
            float4 l = locp[(size_t)b * P + p];
            float pcx = l.x * dw + dcx, pcy = l.y * dh + dcy;
            float pw = expf(l.z) * dw,  ph = expf(l.w) * dh;
            float q0 = pcx - pw * 0.5f, q1 = pcy - ph * 0.5f;
            float q2 = pcx + pw * 0.5f, q3 = pcy + ph * 0.5f;
            float ix0 = fmaxf(q0, t0), iy0 = fmaxf(q1, t1);
            float ix1 = fminf(q2, t2), iy1 = fminf(q3, t3);
            float iw = fmaxf(ix1 - ix0, 0.f), ih = fmaxf(iy1 - iy0, 0.f);
            float inter = iw * ih;
            float pa = (q2 - q0) * (q3 - q1);
            float ta = (t2 - t0) * (t3 - t1);
            float uni = pa + ta - inter;
            float iou = inter / (uni + EPS7);
            float e0 = fminf(q0, t0), e1 = fminf(q1, t1);
            float e2 = fmaxf(q2, t2), e3 = fmaxf(q3, t3);
            float ewd = fmaxf(e2 - e0, 0.f), ehd = fmaxf(e3 - e1, 0.f);
            float encl = ewd * ehd;
            float giou = iou - (encl - uni) / (encl + EPS7);
            acc += (double)(1.f - giou);
        }
    }

    for (int o = 32; o > 0; o >>= 1) {
        acc += __shfl_down(acc, o, 64);
        cnt_pos += __shfl_down(cnt_pos, o, 64);
    }
    int w = t >> 6, lane = t & 63;
    if (lane == 0) { sv[w] = acc; sc[w] = cnt_pos; }
    __syncthreads();
    if (t == 0) {
        int slot = blockIdx.y * gridDim.x + blockIdx.x;
        partS[slot] = sv[0] + sv[1] + sv[2] + sv[3];
        partC[slot] = sc[0] + sc[1] + sc[2] + sc[3];
    }
}

// ---------------------------------------------------------------------------
// Kernel C: reduce per-block partials, divide, write scalar output.
// ---------------------------------------------------------------------------
__global__ __launch_bounds__(256)
void final_kernel(const double* __restrict__ partS,
                  const int*    __restrict__ partC,
                  float* __restrict__ out, int n)
{
    __shared__ double sv[4];
    __shared__ long long sc[4];
    const int t = threadIdx.x;
    double a = 0.0; long long c = 0;
    for (int i = t; i < n; i += 256) { a += partS[i]; c += partC[i]; }
    for (int o = 32; o > 0; o >>= 1) {
        a += __shfl_down(a, o, 64);
        c += __shfl_down(c, o, 64);
    }
    int w = t >> 6, lane = t & 63;
    if (lane == 0) { sv[w] = a; sc[w] = c; }
    __syncthreads();
    if (t == 0) {
        double s = sv[0] + sv[1] + sv[2] + sv[3];
        long long np = sc[0] + sc[1] + sc[2] + sc[3];
        out[0] = (np == 0) ? 0.0f : (float)(s / (double)np);
    }
}

// ---------------------------------------------------------------------------
extern "C" void kernel_launch(void* const* d_in, const int* in_sizes, int n_in,
                              void* d_out, int out_size, void* d_ws, size_t ws_size,
                              hipStream_t stream)
{
    const float* locp = (const float*)d_in[0];   // [B,P,4]
    const float* conf = (const float*)d_in[1];   // [B,P,C]
    const float* dbox = (const float*)d_in[2];   // [P,4]
    const float* gt   = (const float*)d_in[3];   // [B,M,4]
    const int*   gtl  = (const int*)d_in[4];     // [B,M]

    const int P  = in_sizes[2] / 4;
    const long long BP = (long long)in_sizes[0] / 4;
    const int B  = (int)(BP / P);
    const int M  = in_sizes[4] / B;

    const int nblk = (P + 255) / 256;
    const int nPart = nblk * B;

    // ws layout: bpkey[B*M] u64 | partS[nPart] f64 | partC[nPart] i32 | match[B*P] u8
    char* ws = (char*)d_ws;
    unsigned long long* bpkey = (unsigned long long*)ws;
    size_t off = ((size_t)B * M * 8 + 15) & ~(size_t)15;
    double* partS = (double*)(ws + off);
    off += (size_t)nPart * 8;
    int* partC = (int*)(ws + off);
    off += (size_t)nPart * 4;
    off = (off + 15) & ~(size_t)15;
    unsigned char* match = (unsigned char*)(ws + off);

    dim3 grid(nblk, B);
    init_kernel<<<(B * M + 255) / 256, 256, 0, stream>>>(bpkey, B * M);
    match_kernel<<<grid, 256, 0, stream>>>((const float4*)dbox, (const float4*)gt,
                                           bpkey, match, P, M);
    loss_kernel<<<grid, 256, 0, stream>>>((const float4*)locp, conf,
                                          (const float4*)dbox, (const float4*)gt,
                                          gtl, bpkey, match, partS, partC, P, M);
    final_kernel<<<1, 256, 0, stream>>>(partS, partC, (float*)d_out, nPart);
}